// Round 3
// baseline (87.001 us; speedup 1.0000x reference)
//
#include <hip/hip_runtime.h>
#include <math.h>

#define LOG2E  1.44269504088896340736f
#define LN2    0.69314718055994530942f
#define LOG2PI 1.8378770664093453f

#define N 2048
#define D 64

// single-instruction transcendentals (v_exp_f32 / v_log_f32)
__device__ __forceinline__ float fexp2(float x) { return __builtin_amdgcn_exp2f(x); }
__device__ __forceinline__ float flog2(float x) { return __builtin_amdgcn_logf(x); }

// ---------------------------------------------------------------------------
// K1: derived arrays. a*log2e = (z-mean)^2*p + c22 = z2*p + z*q + r2 with
//   p = -0.5*exp(-lv)*log2e, q = -2*mean*p, c22 = -0.5*(lv+LOG2PI)*log2e,
//   r2 = mean^2*p + c22.
// Outputs:
//   packed[j*64+d] = {mean, p, c22, 0}            (K3, coalesced in d)
//   pqT[d*N+j]     = {p, q}                       (K2, coalesced in j)
//   zT[d*N+i], z2T[d*N+i]                         (K2 scalar operands)
//   r[j] = sum_d r2
// Block: 1024 thr covers 64 j x 64 d; LDS transpose for coalesced stores.
// ---------------------------------------------------------------------------
__global__ __launch_bounds__(1024) void k1_precompute(
    const float* __restrict__ z, const float* __restrict__ z_mean,
    const float* __restrict__ z_lv,
    float4* __restrict__ packed, float2* __restrict__ pqT,
    float* __restrict__ zT, float* __restrict__ z2T, float* __restrict__ r)
{
    __shared__ float aL[64][65], bL[64][65], cL[64][65];
    int tid  = threadIdx.x;
    int lane = tid & 63;     // d in compute phases, j in store phases
    int row  = tid >> 6;     // 0..15
    int jb   = blockIdx.x * 64;

    // Phase A: compute p,q,c22,r2; coalesced packed store; stash p,q,r2 in LDS
    #pragma unroll
    for (int ppp = 0; ppp < 4; ++ppp) {
        int jl  = ppp * 16 + row;
        int idx = (jb + jl) * D + lane;
        float mean = z_mean[idx], lv = z_lv[idx];
        float p   = -0.5f * fexp2(-lv * LOG2E) * LOG2E;
        float q   = -2.0f * mean * p;
        float c22 = -0.5f * (lv + LOG2PI) * LOG2E;
        float r2  = fmaf(mean * mean, p, c22);
        packed[idx] = make_float4(mean, p, c22, 0.0f);
        aL[jl][lane] = p; bL[jl][lane] = q; cL[jl][lane] = r2;
    }
    __syncthreads();
    // Phase B: transposed pq store, coalesced in j
    #pragma unroll
    for (int ppp = 0; ppp < 4; ++ppp) {
        int dd = ppp * 16 + row;
        pqT[(size_t)dd * N + jb + lane] = make_float2(aL[lane][dd], bL[lane][dd]);
    }
    // Phase C: r[j] = sum_d r2
    if (tid < 64) {
        float s = 0.0f;
        #pragma unroll
        for (int dd = 0; dd < 64; ++dd) s += cL[tid][dd];
        r[jb + tid] = s;
    }
    __syncthreads();
    // Phase D: stash z, z^2 (reuse aL,bL)
    #pragma unroll
    for (int ppp = 0; ppp < 4; ++ppp) {
        int jl  = ppp * 16 + row;
        int idx = (jb + jl) * D + lane;
        float zv = z[idx];
        aL[jl][lane] = zv; bL[jl][lane] = zv * zv;
    }
    __syncthreads();
    #pragma unroll
    for (int ppp = 0; ppp < 4; ++ppp) {
        int dd = ppp * 16 + row;
        zT [(size_t)dd * N + jb + lane] = aL[lane][dd];
        z2T[(size_t)dd * N + jb + lane] = bL[lane][dd];
    }
}

// ---------------------------------------------------------------------------
// K3: sums[jq][i][d] = sum_{j in quarter jq} 2^{(z-mean)^2*p + c22}
// (fixed max M=0: args in [-~5000, ~1.2]; underflow-to-0 harmless, the
//  diagonal j=i term guarantees the full sum stays >> 0).
// Block: 1024 thr = 16 waves; 16 i's; wave owns 32 j's; lane = d.
// Grid: 128 i-tiles x 4 j-quarters = 512 blocks -> 2 blocks/CU.
// ---------------------------------------------------------------------------
__global__ __launch_bounds__(1024, 8) void k3_perd(
    const float* __restrict__ z, const float4* __restrict__ packed,
    float* __restrict__ sums)
{
    __shared__ float sm[16][16][D];   // 64 KB
    int lane = threadIdx.x & 63;
    int w    = threadIdx.x >> 6;      // 0..15
    int tile = blockIdx.x >> 2;
    int jq   = blockIdx.x & 3;
    int i0   = tile * 16;

    float zr[16], s[16];
    #pragma unroll
    for (int i = 0; i < 16; ++i) {
        zr[i] = z[(i0 + i) * D + lane];
        s[i]  = 0.0f;
    }

    const float4* pk = packed + ((size_t)(jq * 512 + w * 32)) * D + lane;
    #pragma unroll 4
    for (int jj = 0; jj < 32; ++jj) {
        float4 c = pk[(size_t)jj * D];   // {mean, p, c22, -}
        #pragma unroll
        for (int i = 0; i < 16; ++i) {
            float diff = zr[i] - c.x;
            float arg  = fmaf(diff * diff, c.y, c.z);
            s[i] += fexp2(arg);
        }
    }

    #pragma unroll
    for (int i = 0; i < 16; ++i) sm[i][w][lane] = s[i];
    __syncthreads();

    float tot = 0.0f;
    #pragma unroll
    for (int w2 = 0; w2 < 16; ++w2) tot += sm[w][w2][lane];
    sums[((size_t)jq * N + i0 + w) * D + lane] = tot;
}

// ---------------------------------------------------------------------------
// K2: b2[i,j] = sum_d z2*p + z*q  (r[j] added at the end).
// Thread owns ONE j; z/z2 come from transposed arrays as UNIFORM scalar
// loads (s_load, SMEM pipe); pq is one coalesced 8B load per d.
// Per-quarter raw b2 -> LDS -> wave online-LSE merge -> k2m/k2s[jq][i].
// Grid: 128 i-tiles x 4 j-quarters = 512 blocks x 512 thr.
// ---------------------------------------------------------------------------
__global__ __launch_bounds__(512) void k2_logqz(
    const float* __restrict__ zT, const float* __restrict__ z2T,
    const float2* __restrict__ pqT, const float* __restrict__ r,
    float* __restrict__ k2m, float* __restrict__ k2s)
{
    __shared__ float pb[16][512];   // 32 KB
    int tid  = threadIdx.x;
    int tile = blockIdx.x >> 2;
    int jq   = blockIdx.x & 3;
    int i0   = tile * 16;
    int j    = jq * 512 + tid;

    float acc[16];
    #pragma unroll
    for (int i = 0; i < 16; ++i) acc[i] = 0.0f;

    #pragma unroll 2
    for (int d = 0; d < D; ++d) {
        float2 pq = pqT[(size_t)d * N + j];
        const float* zrow  = zT  + (size_t)d * N + i0;
        const float* z2row = z2T + (size_t)d * N + i0;
        #pragma unroll
        for (int i = 0; i < 16; ++i)
            acc[i] = fmaf(z2row[i], pq.x, fmaf(zrow[i], pq.y, acc[i]));
    }

    float rj = r[j];
    #pragma unroll
    for (int i = 0; i < 16; ++i) pb[i][tid] = acc[i] + rj;
    __syncthreads();

    int w = tid >> 6, lane = tid & 63;
    #pragma unroll
    for (int half = 0; half < 2; ++half) {
        int i = w + half * 8;
        float mm = -1e30f, ss = 0.0f;
        #pragma unroll
        for (int c = 0; c < 8; ++c) {
            float v  = pb[i][lane + 64 * c];
            float mn = fmaxf(mm, v);
            ss = ss * fexp2(mm - mn) + fexp2(v - mn);
            mm = mn;
        }
        #pragma unroll
        for (int off = 32; off; off >>= 1) {
            float m2 = __shfl_xor(mm, off, 64);
            float s2 = __shfl_xor(ss, off, 64);
            float mn = fmaxf(mm, m2);
            ss = ss * fexp2(mm - mn) + s2 * fexp2(m2 - mn);
            mm = mn;
        }
        if (lane == 0) { k2m[jq * N + i0 + i] = mm; k2s[jq * N + i0 + i] = ss; }
    }
}

// ---------------------------------------------------------------------------
// K3b: per i (one wave, lane=d): merge 4 j-quarter sums, log2, row-sum ->
// lqp; merge 4 (m,se) LSE partials -> lq; diff[i] = lqp - lq.
// ---------------------------------------------------------------------------
__global__ __launch_bounds__(256) void k3b_merge(
    const float* __restrict__ sums, const float* __restrict__ k2m,
    const float* __restrict__ k2s, float* __restrict__ diff)
{
    int lane = threadIdx.x & 63, w = threadIdx.x >> 6;
    int i = blockIdx.x * 4 + w;

    float tot = 0.0f;
    #pragma unroll
    for (int q = 0; q < 4; ++q) tot += sums[((size_t)q * N + i) * D + lane];
    float t = flog2(tot);
    #pragma unroll
    for (int off = 32; off; off >>= 1) t += __shfl_xor(t, off, 64);

    if (lane == 0) {
        float mm = -1e30f, ss = 0.0f;
        #pragma unroll
        for (int q = 0; q < 4; ++q) {
            float m2 = k2m[q * N + i], s2 = k2s[q * N + i];
            float mn = fmaxf(mm, m2);
            ss = ss * fexp2(mm - mn) + s2 * fexp2(m2 - mn);
            mm = mn;
        }
        diff[i] = LN2 * t - LN2 * (mm + flog2(ss));
    }
}

// ---------------------------------------------------------------------------
// K4: out = mean_i diff[i]
// ---------------------------------------------------------------------------
__global__ __launch_bounds__(256) void k4_final(
    const float* __restrict__ diff, float* __restrict__ out)
{
    __shared__ float red[256];
    int tid = threadIdx.x;
    float t = 0.0f;
    for (int k = tid; k < N; k += 256) t += diff[k];
    red[tid] = t;
    __syncthreads();
    #pragma unroll
    for (int off = 128; off; off >>= 1) {
        if (tid < off) red[tid] += red[tid + off];
        __syncthreads();
    }
    if (tid == 0) out[0] = red[0] * (1.0f / (float)N);
}

extern "C" void kernel_launch(void* const* d_in, const int* in_sizes, int n_in,
                              void* d_out, int out_size, void* d_ws, size_t ws_size,
                              hipStream_t stream)
{
    const float* z      = (const float*)d_in[0];
    const float* z_mean = (const float*)d_in[1];
    const float* z_lv   = (const float*)d_in[2];
    float* out = (float*)d_out;

    float* ws = (float*)d_ws;
    float4* packed = (float4*)ws;                   // N*D float4  (2 MB)
    float*  base   = ws + (size_t)N * D * 4;
    float2* pqT    = (float2*)base;                 // N*D float2  (1 MB)
    float*  zT     = base + (size_t)N * D * 2;      // N*D
    float*  z2T    = zT + (size_t)N * D;            // N*D
    float*  r      = z2T + (size_t)N * D;           // N
    float*  sums   = r + N;                         // 4*N*D       (2 MB)
    float*  k2m    = sums + (size_t)4 * N * D;      // 4*N
    float*  k2s    = k2m + (size_t)4 * N;           // 4*N
    float*  diff   = k2s + (size_t)4 * N;           // N

    k1_precompute<<<N / 64, 1024, 0, stream>>>(z, z_mean, z_lv, packed, pqT, zT, z2T, r);
    k3_perd<<<512, 1024, 0, stream>>>(z, packed, sums);
    k2_logqz<<<512, 512, 0, stream>>>(zT, z2T, pqT, r, k2m, k2s);
    k3b_merge<<<N / 4, 256, 0, stream>>>(sums, k2m, k2s, diff);
    k4_final<<<1, 256, 0, stream>>>(diff, out);
}